// Round 12
// baseline (106.224 us; speedup 1.0000x reference)
//
#include <hip/hip_runtime.h>

// Problem constants (from reference setup_inputs): B=2, H=W=128.
#define B_ITEMS 2
#define W_IMG   128
#define N_PTS   16384          // H*W
#define CH_GRID 1024           // max Utot = 4 s * 256 rowgroups (QS=1, R12)
#define BIGF    3.4e38f

typedef float __attribute__((ext_vector_type(2))) f32x2;
typedef float __attribute__((ext_vector_type(4))) f32x4;

// ---------------------------------------------------------------------------
// Kernel 1: compaction (R7 verbatim — proven). Inits rmG, zeroes out[0].
//   raw[pos] = (x, y, z, |q|^2)        row side
//   tf [pos] = (-2x, -2y, -2z, |q|^2)  col side: d = |p|^2 + fma3(p, tf)
// R8/R9 lesson (double-confirmed): NO fused done-counter epilogues — they
// cost ~20us in whatever kernel hosts them. Pad is a separate dispatch.
// ---------------------------------------------------------------------------
__global__ __launch_bounds__(256) void prep_kernel(
        const float* __restrict__ pred,
        const float* __restrict__ gt,
        const int*   __restrict__ mask,
        const float* fxp, const float* fyp,
        const float* cxp, const float* cyp,
        int*    __restrict__ cnt,       // [0]=np0 [1]=np1 [2]=ng0 [3]=ng1
        float4* __restrict__ pR, float4* __restrict__ gR,   // raw   [B][N]
        float4* __restrict__ pT, float4* __restrict__ gT,   // transf[B][N]
        float*  __restrict__ rmG,       // [4][N_PTS] per-row min table
        float*  __restrict__ out) {
    int s    = blockIdx.x >> 6;
    int b    = s & 1;
    int isG  = s >> 1;
    int tid  = threadIdx.x;
    int idx  = (blockIdx.x & 63) * 256 + tid;
    int lane = tid & 63, w = tid >> 6;

    if (blockIdx.x == 0 && tid == 0) out[0] = 0.0f;
    rmG[(blockIdx.x << 8) + tid] = BIGF;

    float x, y, z;
    if (!isG) {
        float fx = *fxp, fy = *fyp, cx = *cxp, cy = *cyp;
        float u = (float)(idx & (W_IMG - 1));
        float v = (float)(idx >> 7);
        z = pred[b * N_PTS + idx];
        x = (u - cx) / fx * z;
        y = (v - cy) / fy * z;
    } else {
        x = gt[(b * 3 + 0) * N_PTS + idx];
        y = gt[(b * 3 + 1) * N_PTS + idx];
        z = gt[(b * 3 + 2) * N_PTS + idx];
    }
    int  mv = mask[b * N_PTS + idx];
    bool ok = (mv > 0) && (((x + y) + z) != 0.0f);

    unsigned long long bal = __ballot(ok);
    int nw  = __popcll(bal);
    int pre = __popcll(bal & ((1ull << lane) - 1ull));

    __shared__ int wbase[4];
    __shared__ int blockbase;
    if (lane == 0) wbase[w] = nw;
    __syncthreads();
    if (tid == 0) {
        int s0 = 0;
#pragma unroll
        for (int i = 0; i < 4; ++i) { int t = wbase[i]; wbase[i] = s0; s0 += t; }
        blockbase = s0 ? atomicAdd(&cnt[s], s0) : 0;
    }
    __syncthreads();

    if (ok) {
        int pos = blockbase + wbase[w] + pre;
        float ps = fmaf(z, z, fmaf(y, y, x * x));
        float4* __restrict__ raw = (isG ? gR : pR) + b * N_PTS;
        float4* __restrict__ tf  = (isG ? gT : pT) + b * N_PTS;
        raw[pos] = make_float4(x, y, z, ps);
        tf[pos]  = make_float4(-2.0f * x, -2.0f * y, -2.0f * z, ps);
    }
}

// ---------------------------------------------------------------------------
// Kernel 1b: sentinel-pad (R7 verbatim — separate dispatch ON PURPOSE).
// ---------------------------------------------------------------------------
__global__ __launch_bounds__(1024) void pad_kernel(
        const int* __restrict__ cnt,
        float4* __restrict__ pT, float4* __restrict__ gT) {
    int s = blockIdx.x;                      // 0:pT b0  1:pT b1  2:gT b0  3:gT b1
    float4* arr = ((s >> 1) ? gT : pT) + (s & 1) * N_PTS;
    int n = cnt[s];
    int pos = n + threadIdx.x;
    if (pos < ((n + 1023) & ~1023))          // <= N_PTS always
        arr[pos] = make_float4(0.0f, 0.0f, 0.0f, BIGF);
}

// ---------------------------------------------------------------------------
// Kernel 2 (R20): depth-3 counted-vmcnt chamfer (R7/R10/R11 skeleton) with
// ONE delta: QS 2 -> 1. Each 64-row unit now processes the FULL column
// range (ntiles 8 -> 16-32).
// R10+R11 lessons (two clean nulls): chamfer is insensitive to VALU issue
// count (pk_fma halving: null) AND to ds_read count (8-col mapping: null)
// -> not throughput-bound on any pipe; it's schedule-bound: pipeline ramp
// (first-tile latency, thousands of cycles under full-chip streaming per
// R4-R6) amortized over only 8 tiles, times TWO sequential block rounds
// (2048 blocks on 1024 resident slots). QS=1 gives 1024 blocks = exactly
// the resident capacity: ONE round, one ramp, double amortization, half
// the epilogues. Same total tiles, same per-tile schedule, same vmcnt
// logic (rem-based, any ntiles). Everything else byte-identical to R11.
// ---------------------------------------------------------------------------
#define VMCNT(n) asm volatile("s_waitcnt vmcnt(" #n ")" ::: "memory")

__device__ __forceinline__ void stage_tile(const float4* __restrict__ src,
                                           float4* lds_base, int w, int lane) {
    // wave w stages float4 indices [w*128, w*128+128) of the 512-slot tile
    const float4* s0 = src + w * 128 + lane;
    __builtin_amdgcn_global_load_lds(
        (const __attribute__((address_space(1))) void*)(s0),
        (__attribute__((address_space(3))) void*)(lds_base + w * 128), 16, 0, 0);
    __builtin_amdgcn_global_load_lds(
        (const __attribute__((address_space(1))) void*)(s0 + 64),
        (__attribute__((address_space(3))) void*)(lds_base + w * 128 + 64), 16, 0, 0);
}

__global__ __launch_bounds__(256, 4) void chamfer_kernel(
        const int*    __restrict__ cnt,
        const float4* __restrict__ pR, const float4* __restrict__ gR,
        const float4* __restrict__ pT, const float4* __restrict__ gT,
        float* __restrict__ rmG) {
    int np0 = cnt[0], np1 = cnt[1], ng0 = cnt[2], ng1 = cnt[3];
    int naArr[4] = {np0, ng0, np1, ng1};
    int nbArr[4] = {ng0, np0, ng1, np1};
    const float4* Arow[4] = {pR, gR, pR + N_PTS, gR + N_PTS};
    const float4* Bcol[4] = {gT, pT, gT + N_PTS, pT + N_PTS};

    int units[4];
    int Utot = 0;
#pragma unroll
    for (int i = 0; i < 4; ++i) {
        units[i] = (naArr[i] > 0 && nbArr[i] > 0) ? ((naArr[i] + 63) >> 6) : 0;
        Utot += units[i];
    }

    int u = blockIdx.x;
    if (u >= Utot) return;
    int s = 0;
    while (u >= units[s]) { u -= units[s]; ++s; }
    int na = naArr[s], nb = nbArr[s];
    const float4* __restrict__ A  = Arow[s];
    const float4* __restrict__ Bp = Bcol[s];
    int rowbase = u * 64;                    // QS=1: unit = full col range

    int nbPad  = (nb + 1023) & ~1023;        // pad_kernel guarantees data
    int ntiles = nbPad >> 9;                 // 512-col tiles, >= 2

    int tid  = threadIdx.x;
    int lane = tid & 63;
    int w    = tid >> 6;

    // wave w owns rows rowbase + w*16 + {0..15} as 8 f32x2 ROW-PAIRS
    // (pair a = rows w*16+2a, w*16+2a+1). All lanes of the wave hold the
    // same rows; lane = column. rmA[a]/rmB[a] = running min of the pair's
    // two rows. (rows >= na read finite ws poison, gated at the atomicMin)
    f32x2 pxd[8], pyd[8], pzd[8];
    float rmA[8], rmB[8];
#pragma unroll
    for (int a = 0; a < 8; ++a) {
        float4 v0 = A[rowbase + w * 16 + 2 * a];
        float4 v1 = A[rowbase + w * 16 + 2 * a + 1];
        pxd[a] = f32x2{v0.x, v1.x};
        pyd[a] = f32x2{v0.y, v1.y};
        pzd[a] = f32x2{v0.z, v1.z};
        rmA[a] = BIGF; rmB[a] = BIGF;
    }

    __shared__ float4 sB[4][512];            // 4-slot ring (32 KB)
    __shared__ float  smin[64];

    const float4* __restrict__ Bq = Bp;      // cb0 = 0 (full range)

    // prologue: issue stages for tiles 0..2
    if (0 < ntiles) stage_tile(Bq, sB[0], w, lane);
    if (1 < ntiles) stage_tile(Bq + 512, sB[1], w, lane);
    if (2 < ntiles) stage_tile(Bq + 1024, sB[2], w, lane);

    // d = pz*(z,z)+(w,w) ; d = py*(y,y)+d ; d = px*(x,x)+d   (packed pair)
#define PKDIST(D, XY, ZW, a) { \
    asm("v_pk_fma_f32 %0, %1, %2, %3 op_sel:[0,0,1] op_sel_hi:[1,0,1]" \
        : "=v"(D) : "v"(pzd[a]), "v"(ZW), "v"(ZW)); \
    asm("v_pk_fma_f32 %0, %1, %2, %3 op_sel:[0,1,0] op_sel_hi:[1,1,1]" \
        : "=v"(D) : "v"(pyd[a]), "v"(XY), "v"(D)); \
    asm("v_pk_fma_f32 %0, %1, %2, %3 op_sel:[0,0,0] op_sel_hi:[1,0,1]" \
        : "=v"(D) : "v"(pxd[a]), "v"(XY), "v"(D)); }

#pragma unroll 1
    for (int t = 0; t < ntiles; ++t) {
        int rem = ntiles - 1 - t;            // stages issued beyond t (<=2)
        if (rem >= 2)      { VMCNT(4); }     // keep t+1,t+2 in flight
        else if (rem == 1) { VMCNT(2); }
        else               { VMCNT(0); }
        __builtin_amdgcn_s_barrier();        // raw: no compiler vmcnt(0) drain
        __builtin_amdgcn_sched_barrier(0);   // nothing crosses the barrier
        if (t + 3 < ntiles)
            stage_tile(Bq + (t + 3) * 512, sB[(t + 3) & 3], w, lane);
        // lane covers cols {lane + 64k}, k=0..7: 8 ds_read_b128/tile
        const f32x4* bufc = (const f32x4*)&sB[t & 3][lane];
#pragma unroll
        for (int g = 0; g < 8; g += 2) {
            f32x4 c0 = bufc[g * 64];         // 64 distinct consecutive float4
            f32x4 c1 = bufc[g * 64 + 64];
            f32x2 c0xy = c0.xy, c0zw = c0.zw;        // subreg pairs, no movs
            f32x2 c1xy = c1.xy, c1zw = c1.zw;
#pragma unroll
            for (int a = 0; a < 8; ++a) {
                f32x2 d0, d1;
                PKDIST(d0, c0xy, c0zw, a)
                PKDIST(d1, c1xy, c1zw, a)
                rmA[a] = fminf(fminf(rmA[a], d0.x), d1.x);   // v_min3_f32
                rmB[a] = fminf(fminf(rmB[a], d0.y), d1.y);
            }
        }
    }
#undef PKDIST

    // fold over all 64 lanes (full-wave butterfly, 6 levels)
#pragma unroll
    for (int a = 0; a < 8; ++a) {
        float vA = rmA[a], vB = rmB[a];
        vA = fminf(vA, __shfl_xor(vA, 1, 64));
        vB = fminf(vB, __shfl_xor(vB, 1, 64));
        vA = fminf(vA, __shfl_xor(vA, 2, 64));
        vB = fminf(vB, __shfl_xor(vB, 2, 64));
        vA = fminf(vA, __shfl_xor(vA, 4, 64));
        vB = fminf(vB, __shfl_xor(vB, 4, 64));
        vA = fminf(vA, __shfl_xor(vA, 8, 64));
        vB = fminf(vB, __shfl_xor(vB, 8, 64));
        vA = fminf(vA, __shfl_xor(vA, 16, 64));
        vB = fminf(vB, __shfl_xor(vB, 16, 64));
        vA = fminf(vA, __shfl_xor(vA, 32, 64));
        vB = fminf(vB, __shfl_xor(vB, 32, 64));
        rmA[a] = vA; rmB[a] = vB;
    }
    if (lane == 0) {
#pragma unroll
        for (int a = 0; a < 8; ++a) {
            smin[w * 16 + 2 * a]     = rmA[a];
            smin[w * 16 + 2 * a + 1] = rmB[a];
        }
    }
    __syncthreads();                         // full-semantics combine barrier
    if (tid < 64) {
        int row = rowbase + tid;             // matches smin[tid] mapping
        float v  = smin[tid];
        if (row < na) {
            float ps = A[row].w;             // |p|^2 (L1-hot reload)
            float vr = fmaxf(v + ps, 0.0f);  // nonneg -> int order ok
            atomicMin((int*)&rmG[(s << 14) + row], __float_as_int(vr));
        }
    }
}

// ---------------------------------------------------------------------------
// Kernel 3: sum the per-row mins (valid rows only) into out (proven R1/R7).
// SEPARATE dispatch on purpose — R8/R9 lesson.
// ---------------------------------------------------------------------------
__global__ __launch_bounds__(256) void finish_kernel(
        const int*   __restrict__ cnt,
        const float* __restrict__ rmG,
        float*       __restrict__ out) {
    int gid = blockIdx.x * 256 + threadIdx.x;    // 256 blocks x 256
    int s   = gid >> 14;
    int row = gid & (N_PTS - 1);
    int np0 = cnt[0], np1 = cnt[1], ng0 = cnt[2], ng1 = cnt[3];
    int naArr[4] = {np0, ng0, np1, ng1};
    int nbArr[4] = {ng0, np0, ng1, np1};
    float v = (row < naArr[s] && nbArr[s] > 0) ? rmG[gid] : 0.0f;
#pragma unroll
    for (int off = 32; off > 0; off >>= 1)
        v += __shfl_down(v, off, 64);
    __shared__ float wsum[4];
    if ((threadIdx.x & 63) == 0) wsum[threadIdx.x >> 6] = v;
    __syncthreads();
    if (threadIdx.x == 0) {
        float t = (wsum[0] + wsum[1]) + (wsum[2] + wsum[3]);
        atomicAdd(out, t * (1.0f / B_ITEMS));
    }
}

extern "C" void kernel_launch(void* const* d_in, const int* in_sizes, int n_in,
                              void* d_out, int out_size, void* d_ws, size_t ws_size,
                              hipStream_t stream) {
    const float* pred = (const float*)d_in[0];
    const float* gt   = (const float*)d_in[1];
    const int*   mask = (const int*)  d_in[2];
    const float* fx   = (const float*)d_in[3];
    const float* fy   = (const float*)d_in[4];
    const float* cx   = (const float*)d_in[5];
    const float* cy   = (const float*)d_in[6];
    float* out = (float*)d_out;

    // ws: [0,256) cnt | pR 512K | gR 512K | pT 512K | gT 512K | rmG 256K
    char* ws = (char*)d_ws;
    size_t SEG = (size_t)B_ITEMS * N_PTS * 16;
    int*    cnt = (int*)ws;
    float4* pR  = (float4*)(ws + 256);
    float4* gR  = (float4*)(ws + 256 + SEG);
    float4* pT  = (float4*)(ws + 256 + 2 * SEG);
    float4* gT  = (float4*)(ws + 256 + 3 * SEG);
    float*  rmG = (float*) (ws + 256 + 4 * SEG);

    hipMemsetAsync(cnt, 0, 16, stream);

    prep_kernel<<<dim3(256), 256, 0, stream>>>(
        pred, gt, mask, fx, fy, cx, cy, cnt, pR, gR, pT, gT, rmG, out);

    pad_kernel<<<dim3(4), 1024, 0, stream>>>(cnt, pT, gT);

    chamfer_kernel<<<dim3(CH_GRID), 256, 0, stream>>>(
        cnt, pR, gR, pT, gT, rmG);

    finish_kernel<<<dim3(256), 256, 0, stream>>>(cnt, rmG, out);
}

// Round 13
// 101.569 us; speedup vs baseline: 1.0458x; 1.0458x over previous
//
#include <hip/hip_runtime.h>

// Problem constants (from reference setup_inputs): B=2, H=W=128.
#define B_ITEMS 2
#define W_IMG   128
#define N_PTS   16384          // H*W
#define QS      2              // col-split across blocks
#define CH_GRID 2048           // max Utot = 4 s * 256 rowgroups * QS
#define BIGF    3.4e38f

// ---------------------------------------------------------------------------
// R13 = R7 VERBATIM REVERT — the session's best measured total (100.8 us).
// Single-variable sweep results since R7 (all reverted):
//   R8  fused finish into chamfer : 253 us (epilogue pessimizes host kernel)
//   R9  fused pad into prep       : 121 us (same effect, double-confirmed)
//   R10 v_pk_fma_f32 inner loop   : 102.6 (null — not VALU-issue-bound)
//   R11 16rows x 8cols mapping    : 102.0 (null — not LDS-read-bound)
//   R12 QS=1 single round         : 106.2 (under-fills slots; longer tails)
// Conclusion: QS=2 + depth-3 counted-vmcnt ring + 8x16 scalar-fma mapping
// + 5 separate dispatches is the saturated optimum of this decomposition.
// ---------------------------------------------------------------------------

// Kernel 1: compaction. Inits rmG, zeroes out[0].
//   raw[pos] = (x, y, z, |q|^2)        row side
//   tf [pos] = (-2x, -2y, -2z, |q|^2)  col side: d = |p|^2 + fma3(p, tf)
__global__ __launch_bounds__(256) void prep_kernel(
        const float* __restrict__ pred,
        const float* __restrict__ gt,
        const int*   __restrict__ mask,
        const float* fxp, const float* fyp,
        const float* cxp, const float* cyp,
        int*    __restrict__ cnt,       // [0]=np0 [1]=np1 [2]=ng0 [3]=ng1
        float4* __restrict__ pR, float4* __restrict__ gR,   // raw   [B][N]
        float4* __restrict__ pT, float4* __restrict__ gT,   // transf[B][N]
        float*  __restrict__ rmG,       // [4][N_PTS] per-row min table
        float*  __restrict__ out) {
    int s    = blockIdx.x >> 6;
    int b    = s & 1;
    int isG  = s >> 1;
    int tid  = threadIdx.x;
    int idx  = (blockIdx.x & 63) * 256 + tid;
    int lane = tid & 63, w = tid >> 6;

    if (blockIdx.x == 0 && tid == 0) out[0] = 0.0f;
    rmG[(blockIdx.x << 8) + tid] = BIGF;

    float x, y, z;
    if (!isG) {
        float fx = *fxp, fy = *fyp, cx = *cxp, cy = *cyp;
        float u = (float)(idx & (W_IMG - 1));
        float v = (float)(idx >> 7);
        z = pred[b * N_PTS + idx];
        x = (u - cx) / fx * z;
        y = (v - cy) / fy * z;
    } else {
        x = gt[(b * 3 + 0) * N_PTS + idx];
        y = gt[(b * 3 + 1) * N_PTS + idx];
        z = gt[(b * 3 + 2) * N_PTS + idx];
    }
    int  mv = mask[b * N_PTS + idx];
    bool ok = (mv > 0) && (((x + y) + z) != 0.0f);

    unsigned long long bal = __ballot(ok);
    int nw  = __popcll(bal);
    int pre = __popcll(bal & ((1ull << lane) - 1ull));

    __shared__ int wbase[4];
    __shared__ int blockbase;
    if (lane == 0) wbase[w] = nw;
    __syncthreads();
    if (tid == 0) {
        int s0 = 0;
#pragma unroll
        for (int i = 0; i < 4; ++i) { int t = wbase[i]; wbase[i] = s0; s0 += t; }
        blockbase = s0 ? atomicAdd(&cnt[s], s0) : 0;
    }
    __syncthreads();

    if (ok) {
        int pos = blockbase + wbase[w] + pre;
        float ps = fmaf(z, z, fmaf(y, y, x * x));
        float4* __restrict__ raw = (isG ? gR : pR) + b * N_PTS;
        float4* __restrict__ tf  = (isG ? gT : pT) + b * N_PTS;
        raw[pos] = make_float4(x, y, z, ps);
        tf[pos]  = make_float4(-2.0f * x, -2.0f * y, -2.0f * z, ps);
    }
}

// ---------------------------------------------------------------------------
// Kernel 1b: sentinel-pad each compacted B-side (transformed) array up to a
// multiple of 1024 cols. Removes ALL ragged-tail masking from the chamfer
// hot loop. Sentinel (0,0,0,BIGF) never wins a min. SEPARATE dispatch ON
// PURPOSE (R9: fusing it into prep cost ~20 us).
// ---------------------------------------------------------------------------
__global__ __launch_bounds__(1024) void pad_kernel(
        const int* __restrict__ cnt,
        float4* __restrict__ pT, float4* __restrict__ gT) {
    int s = blockIdx.x;                      // 0:pT b0  1:pT b1  2:gT b0  3:gT b1
    float4* arr = ((s >> 1) ? gT : pT) + (s & 1) * N_PTS;
    int n = cnt[s];
    int pos = n + threadIdx.x;
    if (pos < ((n + 1023) & ~1023))          // <= N_PTS always
        arr[pos] = make_float4(0.0f, 0.0f, 0.0f, BIGF);
}

// ---------------------------------------------------------------------------
// Kernel 2: block-staged chamfer with DEPTH-3 pipelined staging via
// global_load_lds + counted vmcnt (never drained to 0 in the main loop).
// R4-R6 lesson: shallow-pipelined structures hit 172-180 us at 15% VALU;
// 3 tiles (~3000+ cy) in flight fixed it. R8 lesson: NO fused epilogue.
// Per tile t: VMCNT(4|2|0 counted) -> raw s_barrier -> sched_barrier(0)
//   -> issue stage(t+3) -> compute tile t (16 ds_read_b128 + min3 pairs).
// ---------------------------------------------------------------------------
#define VMCNT(n) asm volatile("s_waitcnt vmcnt(" #n ")" ::: "memory")

__device__ __forceinline__ void stage_tile(const float4* __restrict__ src,
                                           float4* lds_base, int w, int lane) {
    // wave w stages float4 indices [w*128, w*128+128) of the 512-slot tile
    const float4* s0 = src + w * 128 + lane;
    __builtin_amdgcn_global_load_lds(
        (const __attribute__((address_space(1))) void*)(s0),
        (__attribute__((address_space(3))) void*)(lds_base + w * 128), 16, 0, 0);
    __builtin_amdgcn_global_load_lds(
        (const __attribute__((address_space(1))) void*)(s0 + 64),
        (__attribute__((address_space(3))) void*)(lds_base + w * 128 + 64), 16, 0, 0);
}

__global__ __launch_bounds__(256, 4) void chamfer_kernel(
        const int*    __restrict__ cnt,
        const float4* __restrict__ pR, const float4* __restrict__ gR,
        const float4* __restrict__ pT, const float4* __restrict__ gT,
        float* __restrict__ rmG) {
    int np0 = cnt[0], np1 = cnt[1], ng0 = cnt[2], ng1 = cnt[3];
    int naArr[4] = {np0, ng0, np1, ng1};
    int nbArr[4] = {ng0, np0, ng1, np1};
    const float4* Arow[4] = {pR, gR, pR + N_PTS, gR + N_PTS};
    const float4* Bcol[4] = {gT, pT, gT + N_PTS, pT + N_PTS};

    int units[4];
    int Utot = 0;
#pragma unroll
    for (int i = 0; i < 4; ++i) {
        units[i] = (naArr[i] > 0 && nbArr[i] > 0) ? (((naArr[i] + 63) >> 6) * QS) : 0;
        Utot += units[i];
    }

    int u = blockIdx.x;
    if (u >= Utot) return;
    int s = 0;
    while (u >= units[s]) { u -= units[s]; ++s; }
    int na = naArr[s], nb = nbArr[s];
    const float4* __restrict__ A  = Arow[s];
    const float4* __restrict__ Bp = Bcol[s];
    int q       = u & (QS - 1);
    int rowbase = (u >> 1) * 64;

    int nbPad  = (nb + 1023) & ~1023;        // pad_kernel guarantees data
    int Lq     = nbPad >> 1;                 // half length, mult of 512
    int cb0    = q * Lq;
    int ntiles = Lq >> 9;                    // >= 1 (nb > 0 by gating)

    int tid  = threadIdx.x;
    int lane = tid & 63;
    int w    = tid >> 6;
    int tc   = tid & 31, tr = tid >> 5;

    // 8 rows/thread: row = rowbase + a*8 + tr (rows >= na read finite ws
    // poison, gated at the atomicMin).
    float px[8], py[8], pz[8], rm[8];
#pragma unroll
    for (int a = 0; a < 8; ++a) {
        float4 v = A[rowbase + a * 8 + tr];
        px[a] = v.x; py[a] = v.y; pz[a] = v.z;
        rm[a] = BIGF;
    }

    __shared__ float4 sB[4][512];            // 4-slot ring (32 KB)
    __shared__ float  smin[64];

    const float4* __restrict__ Bq = Bp + cb0;

    // prologue: issue stages for tiles 0..2
    if (0 < ntiles) stage_tile(Bq, sB[0], w, lane);
    if (1 < ntiles) stage_tile(Bq + 512, sB[1], w, lane);
    if (2 < ntiles) stage_tile(Bq + 1024, sB[2], w, lane);

#pragma unroll 1
    for (int t = 0; t < ntiles; ++t) {
        int rem = ntiles - 1 - t;            // stages issued beyond t (<=2)
        if (rem >= 2)      { VMCNT(4); }     // keep t+1,t+2 in flight
        else if (rem == 1) { VMCNT(2); }
        else               { VMCNT(0); }
        __builtin_amdgcn_s_barrier();        // raw: no compiler vmcnt(0) drain
        __builtin_amdgcn_sched_barrier(0);   // nothing crosses the barrier
        if (t + 3 < ntiles)
            stage_tile(Bq + (t + 3) * 512, sB[(t + 3) & 3], w, lane);
        const float4* bufc = &sB[t & 3][tc];
#pragma unroll
        for (int cb = 0; cb < 16; cb += 2) {
            float4 c0 = bufc[cb * 32];       // b128, 2-way alias: free
            float4 c1 = bufc[cb * 32 + 32];
#pragma unroll
            for (int a = 0; a < 8; ++a) {
                float d0 = fmaf(px[a], c0.x,
                             fmaf(py[a], c0.y, fmaf(pz[a], c0.z, c0.w)));
                float d1 = fmaf(px[a], c1.x,
                             fmaf(py[a], c1.y, fmaf(pz[a], c1.z, c1.w)));
                rm[a] = fminf(fminf(rm[a], d0), d1);      // v_min3_f32
            }
        }
    }

    // fold over tc (lane bits 0..4)
#pragma unroll
    for (int a = 0; a < 8; ++a) {
        float v = rm[a];
        v = fminf(v, __shfl_xor(v, 1, 64));
        v = fminf(v, __shfl_xor(v, 2, 64));
        v = fminf(v, __shfl_xor(v, 4, 64));
        v = fminf(v, __shfl_xor(v, 8, 64));
        v = fminf(v, __shfl_xor(v, 16, 64));
        rm[a] = v;
    }
    if (tc == 0) {                           // lanes 0 & 32 of each wave
#pragma unroll
        for (int a = 0; a < 8; ++a) smin[a * 8 + tr] = rm[a];
    }
    __syncthreads();                         // full-semantics combine barrier
    if (tid < 64) {
        int row = rowbase + tid;             // matches smin[tid] mapping
        float v  = smin[tid];
        if (row < na) {
            float ps = A[row].w;             // |p|^2 (L1-hot reload)
            float vr = fmaxf(v + ps, 0.0f);  // nonneg -> int order ok
            atomicMin((int*)&rmG[(s << 14) + row], __float_as_int(vr));
        }
    }
}

// ---------------------------------------------------------------------------
// Kernel 3: sum the per-row mins (valid rows only) into out.
// SEPARATE dispatch on purpose — R8/R9 lesson.
// ---------------------------------------------------------------------------
__global__ __launch_bounds__(256) void finish_kernel(
        const int*   __restrict__ cnt,
        const float* __restrict__ rmG,
        float*       __restrict__ out) {
    int gid = blockIdx.x * 256 + threadIdx.x;    // 256 blocks x 256
    int s   = gid >> 14;
    int row = gid & (N_PTS - 1);
    int np0 = cnt[0], np1 = cnt[1], ng0 = cnt[2], ng1 = cnt[3];
    int naArr[4] = {np0, ng0, np1, ng1};
    int nbArr[4] = {ng0, np0, ng1, np1};
    float v = (row < naArr[s] && nbArr[s] > 0) ? rmG[gid] : 0.0f;
#pragma unroll
    for (int off = 32; off > 0; off >>= 1)
        v += __shfl_down(v, off, 64);
    __shared__ float wsum[4];
    if ((threadIdx.x & 63) == 0) wsum[threadIdx.x >> 6] = v;
    __syncthreads();
    if (threadIdx.x == 0) {
        float t = (wsum[0] + wsum[1]) + (wsum[2] + wsum[3]);
        atomicAdd(out, t * (1.0f / B_ITEMS));
    }
}

extern "C" void kernel_launch(void* const* d_in, const int* in_sizes, int n_in,
                              void* d_out, int out_size, void* d_ws, size_t ws_size,
                              hipStream_t stream) {
    const float* pred = (const float*)d_in[0];
    const float* gt   = (const float*)d_in[1];
    const int*   mask = (const int*)  d_in[2];
    const float* fx   = (const float*)d_in[3];
    const float* fy   = (const float*)d_in[4];
    const float* cx   = (const float*)d_in[5];
    const float* cy   = (const float*)d_in[6];
    float* out = (float*)d_out;

    // ws: [0,256) cnt | pR 512K | gR 512K | pT 512K | gT 512K | rmG 256K
    char* ws = (char*)d_ws;
    size_t SEG = (size_t)B_ITEMS * N_PTS * 16;
    int*    cnt = (int*)ws;
    float4* pR  = (float4*)(ws + 256);
    float4* gR  = (float4*)(ws + 256 + SEG);
    float4* pT  = (float4*)(ws + 256 + 2 * SEG);
    float4* gT  = (float4*)(ws + 256 + 3 * SEG);
    float*  rmG = (float*) (ws + 256 + 4 * SEG);

    hipMemsetAsync(cnt, 0, 16, stream);

    prep_kernel<<<dim3(256), 256, 0, stream>>>(
        pred, gt, mask, fx, fy, cx, cy, cnt, pR, gR, pT, gT, rmG, out);

    pad_kernel<<<dim3(4), 1024, 0, stream>>>(cnt, pT, gT);

    chamfer_kernel<<<dim3(CH_GRID), 256, 0, stream>>>(
        cnt, pR, gR, pT, gT, rmG);

    finish_kernel<<<dim3(256), 256, 0, stream>>>(cnt, rmG, out);
}